// Round 2
// baseline (687.630 us; speedup 1.0000x reference)
//
#include <hip/hip_runtime.h>

#define NB 64
#define NM 128
#define NAI 75   // n_atom_in
#define NPI 14   // n_pair_in
#define NH 50    // hidden
#define NAO 50   // n_atom_out
#define NPO 50   // n_pair_out

// ---------------- kernel 1: t[bi][h] = atom[bi,:] @ (W_AP[:75]+W_AP[75:]) ----------------
__global__ void k_t(const float* __restrict__ atom, const float* __restrict__ W_AP,
                    float* __restrict__ t) {
    int idx = blockIdx.x * 256 + threadIdx.x;
    if (idx >= NB * NM * NH) return;
    int bi = idx / NH, h = idx % NH;
    const float* ar = atom + bi * NAI;
    float acc = 0.f;
#pragma unroll
    for (int f = 0; f < NAI; ++f)
        acc = fmaf(ar[f], W_AP[f * NH + h] + W_AP[(f + NAI) * NH + h], acc);
    t[idx] = acc;
}

// ---------------- kernel 2: per (b, i-pair) block; thread = j ----------------
// Computes P[b,i,:,:] for two i values, plus the A[b,i,:] rows (S_pair reduced in-block).
__global__ __launch_bounds__(256) void k_main(
    const float* __restrict__ atom, const float* __restrict__ pair,
    const float* __restrict__ amask, const float* __restrict__ pmask,
    const float* __restrict__ W_AA, const float* __restrict__ b_AA,
    const float* __restrict__ W_PA, const float* __restrict__ b_PA,
    const float* __restrict__ W_A,  const float* __restrict__ b_A,
    const float* __restrict__ b_AP,
    const float* __restrict__ W_PP, const float* __restrict__ b_PP,
    const float* __restrict__ W_P,  const float* __restrict__ b_P,
    const float* __restrict__ t,
    float* __restrict__ outA, float* __restrict__ outP)
{
    __shared__ float t_lds[NM * NH];        // 25.6 KB: t[b, j, h] for all j
    __shared__ float wp[2 * NH * NPO];      // 20 KB: W_P
    __shared__ float wppt[NH * NPI];        // 2.8 KB: W_PP transposed [h][f]
    __shared__ float bPP[NH], bAP[NH], bPo[NPO];
    __shared__ float atom2[2][NAI];
    __shared__ float wred[4][NPI];          // per-wave partial sums of pair rows
    __shared__ float S2[2][NPI];            // S_pair for the two i's
    __shared__ float conc[2][2 * NH];       // [AA, PA] per i

    const int tid  = threadIdx.x;
    const int b    = blockIdx.x >> 6;       // / 64
    const int i0   = (blockIdx.x & 63) * 2;
    const int half = tid >> 7;              // which of the two i's
    const int j    = tid & 127;
    const int i    = i0 + half;

    // ---- stage LDS ----
    for (int x = tid; x < NM * NH; x += 256) t_lds[x] = t[b * NM * NH + x];
    for (int x = tid; x < 2 * NH * NPO; x += 256) wp[x] = W_P[x];
    for (int x = tid; x < NH * NPI; x += 256) {
        int f = x / NH, h = x % NH;
        wppt[h * NPI + f] = W_PP[x];
    }
    if (tid < NH) bPP[tid] = b_PP[tid];
    else if (tid < 2 * NH) bAP[tid - NH] = b_AP[tid - NH];
    else if (tid < 2 * NH + NPO) bPo[tid - 2 * NH] = b_P[tid - 2 * NH];
    if (tid < 2 * NAI) atom2[tid / NAI][tid % NAI] = atom[(b * NM + i0) * NAI + tid];
    __syncthreads();

    // ---- load this thread's pair row ----
    const float* prow = pair + (((size_t)(b * NM + i) * NM) + j) * NPI;
    float pr[NPI];
#pragma unroll
    for (int f = 0; f < NPI; ++f) pr[f] = prow[f];

    float acc[NPO];
#pragma unroll
    for (int o = 0; o < NPO; ++o) acc[o] = bPo[o];

    // ---- PP phase: pp_h = relu(pair_row @ W_PP[:,h] + b_PP[h]); acc += pp_h * W_P[50+h,:]
#pragma unroll 2
    for (int h = 0; h < NH; ++h) {
        float v = bPP[h];
#pragma unroll
        for (int f = 0; f < NPI; ++f) v = fmaf(pr[f], wppt[h * NPI + f], v);
        v = fmaxf(v, 0.f);
        const float* wrow = &wp[(NH + h) * NPO];
#pragma unroll
        for (int o = 0; o < NPO; ++o) acc[o] = fmaf(v, wrow[o], acc[o]);
    }

    // ---- AP phase: ap_h = relu(t_i[h] + t_j[h] + b_AP[h]); acc += ap_h * W_P[h,:]
#pragma unroll 2
    for (int h = 0; h < NH; ++h) {
        float v = fmaxf(t_lds[i * NH + h] + t_lds[j * NH + h] + bAP[h], 0.f);
        const float* wrow = &wp[h * NPO];
#pragma unroll
        for (int o = 0; o < NPO; ++o) acc[o] = fmaf(v, wrow[o], acc[o]);
    }

    // ---- store P row ----
    {
        const size_t row = (size_t)(b * NM + i) * NM + j;
        const float mk = pmask[row];
        float* po = outP + row * NPO;
#pragma unroll
        for (int o = 0; o < NPO; ++o) po[o] = fmaxf(acc[o], 0.f) * mk;
    }

    // ---- S_pair reduction (sum of pr over the 128 j's of this i) ----
    const int wave = tid >> 6;  // 0..3; waves {2*half, 2*half+1} belong to i
#pragma unroll
    for (int f = 0; f < NPI; ++f) {
        float v = pr[f];
#pragma unroll
        for (int s = 32; s; s >>= 1) v += __shfl_xor(v, s, 64);
        if ((tid & 63) == 0) wred[wave][f] = v;
    }
    __syncthreads();
    if (j < NPI) S2[half][j] = wred[half * 2][j] + wred[half * 2 + 1][j];
    __syncthreads();

    // ---- AA / PA rows for this i ----
    if (j < NH) {
        const int h = j;
        float aa = b_AA[h];
#pragma unroll
        for (int f = 0; f < NAI; ++f) aa = fmaf(atom2[half][f], W_AA[f * NH + h], aa);
        float pa = 128.f * b_PA[h];
#pragma unroll
        for (int f = 0; f < NPI; ++f) pa = fmaf(S2[half][f], W_PA[f * NH + h], pa);
        conc[half][h]      = fmaxf(aa, 0.f);
        conc[half][NH + h] = fmaxf(pa, 0.f);
    }
    __syncthreads();

    // ---- A row ----
    if (j < NAO) {
        const int o = j;
        float a = b_A[o];
#pragma unroll
        for (int hh = 0; hh < 2 * NH; ++hh) a = fmaf(conc[half][hh], W_A[hh * NAO + o], a);
        a = fmaxf(a, 0.f) * amask[b * NM + i];
        outA[(b * NM + i) * NAO + o] = a;
    }
}

extern "C" void kernel_launch(void* const* d_in, const int* in_sizes, int n_in,
                              void* d_out, int out_size, void* d_ws, size_t ws_size,
                              hipStream_t stream) {
    const float* atom  = (const float*)d_in[0];
    const float* pairf = (const float*)d_in[1];
    const float* amask = (const float*)d_in[2];
    const float* pmask = (const float*)d_in[3];
    const float* W_AA  = (const float*)d_in[4];
    const float* b_AA  = (const float*)d_in[5];
    const float* W_PA  = (const float*)d_in[6];
    const float* b_PA  = (const float*)d_in[7];
    const float* W_A   = (const float*)d_in[8];
    const float* b_A   = (const float*)d_in[9];
    const float* W_AP  = (const float*)d_in[10];
    const float* b_AP  = (const float*)d_in[11];
    const float* W_PP  = (const float*)d_in[12];
    const float* b_PP  = (const float*)d_in[13];
    const float* W_P   = (const float*)d_in[14];
    const float* b_P   = (const float*)d_in[15];

    float* t    = (float*)d_ws;                       // (B*M*50) f32 = 1.6 MB
    float* outA = (float*)d_out;                      // (B,M,50)
    float* outP = (float*)d_out + (size_t)NB * NM * NAO;  // (B,M,M,50)

    const int nt = NB * NM * NH;
    k_t<<<(nt + 255) / 256, 256, 0, stream>>>(atom, W_AP, t);

    k_main<<<NB * (NM / 2), 256, 0, stream>>>(
        atom, pairf, amask, pmask,
        W_AA, b_AA, W_PA, b_PA, W_A, b_A, b_AP,
        W_PP, b_PP, W_P, b_P, t, outA, outP);
}

// Round 6
// 401.037 us; speedup vs baseline: 1.7146x; 1.7146x over previous
//
#include <hip/hip_runtime.h>

#define NB 64
#define NM 128
#define NAI 75
#define NPI 14
#define NH 50
#define NAO 50
#define NPO 50

typedef __attribute__((ext_vector_type(8))) short s8v;
typedef __attribute__((ext_vector_type(4))) float f4v;

union ABfrag { s8v v; unsigned short u[8]; unsigned w[4]; };

__device__ __forceinline__ unsigned short f2bf(float x) {
    union { float f; unsigned u; } c{x};
    unsigned r = c.u + 0x7fffu + ((c.u >> 16) & 1u);
    return (unsigned short)(r >> 16);
}
__device__ __forceinline__ float bf2f(unsigned short b) {
    union { unsigned u; float f; } c{(unsigned)b << 16};
    return c.f;
}

// t[bi][h] = atom[bi,:] @ (W_AP[:75]+W_AP[75:]), bf16, rows padded to 72
__global__ void k_t(const float* __restrict__ atom, const float* __restrict__ W_AP,
                    unsigned short* __restrict__ t) {
    int idx = blockIdx.x * 256 + threadIdx.x;
    if (idx >= NB * NM * 72) return;
    int bi = idx / 72, h = idx % 72;
    unsigned short v = 0;
    if (h < NH) {
        const float* ar = atom + bi * NAI;
        float acc = 0.f;
#pragma unroll
        for (int f = 0; f < NAI; ++f)
            acc = fmaf(ar[f], W_AP[f * NH + h] + W_AP[(f + NAI) * NH + h], acc);
        v = f2bf(acc);
    }
    t[idx] = v;
}

// W_P^T in bf16: wt[o][k], o<64 (pad), k<136 (pad). k 0..63 -> W_P[k][o] (AP, k<50),
// k 64..127 -> W_P[50+(k-64)][o] (PP, k-64<50), else 0.
__global__ void k_prep(const float* __restrict__ W_P, unsigned short* __restrict__ wt) {
    int idx = blockIdx.x * 256 + threadIdx.x;
    if (idx >= 64 * 136) return;
    int o = idx / 136, k = idx % 136;
    float v = 0.f;
    if (o < NPO && k < 128) {
        if (k < 64) { if (k < NH) v = W_P[k * NPO + o]; }
        else        { if (k - 64 < NH) v = W_P[(NH + k - 64) * NPO + o]; }
    }
    wt[idx] = f2bf(v);
}

__global__ __launch_bounds__(256, 3) void k_main(
    const float* __restrict__ atom, const float* __restrict__ pair,
    const float* __restrict__ amask, const float* __restrict__ pmask,
    const float* __restrict__ W_AA, const float* __restrict__ b_AA,
    const float* __restrict__ W_PA, const float* __restrict__ b_PA,
    const float* __restrict__ W_A,  const float* __restrict__ b_A,
    const float* __restrict__ b_AP,
    const float* __restrict__ W_PP, const float* __restrict__ b_PP,
    const float* __restrict__ b_P,
    const unsigned short* __restrict__ t_ws, const unsigned short* __restrict__ wt_ws,
    float* __restrict__ outA, float* __restrict__ outP)
{
    __shared__ __align__(16) unsigned short t_lds[NM * 72];     // 18.4 KB bf16, pad 72
    __shared__ __align__(16) unsigned short wt_lds[64 * 136];   // 17.4 KB bf16 W_P^T
    __shared__ __align__(16) float prow_lds[NM * NPI];          // 7 KB
    __shared__ __align__(16) float wpp_lds[NPI * 64];           // 3.6 KB, rows pad 64 (zeros)
    __shared__ __align__(16) float pm_lds[NM];
    __shared__ float bP_lds[64], bPP_lds[64], bAP_lds[64];
    __shared__ float atom_lds[NAI];
    __shared__ float wred[16][NPI];
    __shared__ float S_lds[NPI];
    __shared__ float conc[2 * NH];

    const int tid  = threadIdx.x;
    const int b    = blockIdx.x >> 7;
    const int i    = blockIdx.x & 127;
    const int wave = tid >> 6;
    const int lane = tid & 63;
    const int ln   = lane & 15;
    const int hi   = lane >> 4;          // 0..3

    // ---------------- stage ----------------
    {
        const float4* src = (const float4*)(t_ws + (size_t)b * NM * 72);
        float4* dst = (float4*)t_lds;
        for (int x = tid; x < NM * 72 * 2 / 16; x += 256) dst[x] = src[x];
    }
    {
        const float4* src = (const float4*)wt_ws;
        float4* dst = (float4*)wt_lds;
        for (int x = tid; x < 64 * 136 * 2 / 16; x += 256) dst[x] = src[x];
    }
    {
        const float4* src = (const float4*)(pair + (size_t)blockIdx.x * NM * NPI);
        float4* dst = (float4*)prow_lds;
        for (int x = tid; x < NM * NPI / 4; x += 256) dst[x] = src[x];
    }
    for (int x = tid; x < NPI * 64; x += 256) {
        int f = x >> 6, h = x & 63;
        wpp_lds[x] = (h < NH) ? W_PP[f * NH + h] : 0.f;
    }
    if (tid < 32) ((float4*)pm_lds)[tid] = ((const float4*)(pmask + (size_t)blockIdx.x * NM))[tid];
    if (tid < 64) {
        bP_lds[tid]  = (tid < NPO) ? b_P[tid]  : 0.f;
        bPP_lds[tid] = (tid < NH)  ? b_PP[tid] : 0.f;
        bAP_lds[tid] = (tid < NH)  ? b_AP[tid] : 0.f;
    }
    if (tid >= 64 && tid < 64 + NAI) atom_lds[tid - 64] = atom[(size_t)blockIdx.x * NAI + (tid - 64)];
    __syncthreads();

    // ---------------- MFMA phase ----------------
    const int j0 = wave * 32 + ln;           // m=0 row
    const int j1 = j0 + 16;                  // m=1 row
    float pr0[NPI], pr1[NPI];
#pragma unroll
    for (int f = 0; f < NPI; ++f) {
        pr0[f] = prow_lds[j0 * NPI + f];
        pr1[f] = prow_lds[j1 * NPI + f];
    }

    f4v acc[2][4];
#pragma unroll
    for (int m = 0; m < 2; ++m)
#pragma unroll
        for (int n = 0; n < 4; ++n) acc[m][n] = f4v{0.f, 0.f, 0.f, 0.f};

#pragma unroll
    for (int ks = 0; ks < 4; ++ks) {
        // B fragments: lane holds W[k = ks*32 + 8*hi + e][o = n*16 + ln]
        s8v bfr[4];
#pragma unroll
        for (int n = 0; n < 4; ++n)
            bfr[n] = *(const s8v*)&wt_lds[(n * 16 + ln) * 136 + ks * 32 + 8 * hi];

        if (ks < 2) {
            // AP half: k -> h = ks*32 + 8*hi + e
            const int h0 = ks * 32 + 8 * hi;
            float tif[8];
            {
                const s8v ti = *(const s8v*)&t_lds[i * 72 + h0];
#pragma unroll
                for (int e = 0; e < 8; ++e)
                    tif[e] = bf2f(((unsigned short)ti[e])) + bAP_lds[h0 + e];
            }
#pragma unroll
            for (int m = 0; m < 2; ++m) {
                const int jm = (m == 0) ? j0 : j1;
                const s8v tj = *(const s8v*)&t_lds[jm * 72 + h0];
                ABfrag af;
#pragma unroll
                for (int e = 0; e < 8; ++e) {
                    float v = fmaxf(tif[e] + bf2f((unsigned short)tj[e]), 0.f);
                    af.u[e] = (h0 + e < NH) ? f2bf(v) : 0;
                }
#pragma unroll
                for (int n = 0; n < 4; ++n)
                    acc[m][n] = __builtin_amdgcn_mfma_f32_16x16x32_bf16(af.v, bfr[n], acc[m][n], 0, 0, 0);
            }
        } else {
            // PP half: k-64 -> h = (ks-2)*32 + 8*hi + e
            const int h0 = (ks - 2) * 32 + 8 * hi;
            float pa0[8], pa1[8];
#pragma unroll
            for (int e = 0; e < 8; ++e) { pa0[e] = bPP_lds[h0 + e]; pa1[e] = pa0[e]; }
#pragma unroll
            for (int f = 0; f < NPI; ++f) {
                const float4 wlo = *(const float4*)&wpp_lds[f * 64 + h0];
                const float4 whi = *(const float4*)&wpp_lds[f * 64 + h0 + 4];
                const float w8[8] = {wlo.x, wlo.y, wlo.z, wlo.w, whi.x, whi.y, whi.z, whi.w};
#pragma unroll
                for (int e = 0; e < 8; ++e) {
                    pa0[e] = fmaf(pr0[f], w8[e], pa0[e]);
                    pa1[e] = fmaf(pr1[f], w8[e], pa1[e]);
                }
            }
#pragma unroll
            for (int m = 0; m < 2; ++m) {
                float* pa = (m == 0) ? pa0 : pa1;
                ABfrag af;
#pragma unroll
                for (int e = 0; e < 8; ++e) {
                    float v = fmaxf(pa[e], 0.f);
                    af.u[e] = (h0 + e < NH) ? f2bf(v) : 0;
                }
#pragma unroll
                for (int n = 0; n < 4; ++n)
                    acc[m][n] = __builtin_amdgcn_mfma_f32_16x16x32_bf16(af.v, bfr[n], acc[m][n], 0, 0, 0);
            }
        }
    }

    // ---------------- epilogue: P stores ----------------
#pragma unroll
    for (int m = 0; m < 2; ++m) {
#pragma unroll
        for (int r = 0; r < 4; ++r) {
            const int row = wave * 32 + m * 16 + 4 * hi + r;
            const float pm = pm_lds[row];
            const size_t base = ((size_t)blockIdx.x * NM + row) * NPO;
#pragma unroll
            for (int n = 0; n < 4; ++n) {
                const int col = n * 16 + ln;
                float v = acc[m][n][r] + bP_lds[col];
                v = fmaxf(v, 0.f) * pm;
                if (col < NPO) outP[base + col] = v;
            }
        }
    }

    // ---------------- A path ----------------
    {
        const int c = tid >> 4, f = tid & 15;
        if (f < NPI) {
            float s = 0.f;
#pragma unroll
            for (int r = 0; r < 8; ++r) s += prow_lds[(c * 8 + r) * NPI + f];
            wred[c][f] = s;
        }
    }
    __syncthreads();
    if (tid < NPI) {
        float s = 0.f;
#pragma unroll
        for (int c = 0; c < 16; ++c) s += wred[c][tid];
        S_lds[tid] = s;
    }
    __syncthreads();
    if (tid < NH) {
        float aa = b_AA[tid];
#pragma unroll
        for (int f = 0; f < NAI; ++f) aa = fmaf(atom_lds[f], W_AA[f * NH + tid], aa);
        float pa = 128.f * b_PA[tid];
#pragma unroll
        for (int f = 0; f < NPI; ++f) pa = fmaf(S_lds[f], W_PA[f * NH + tid], pa);
        conc[tid]      = fmaxf(aa, 0.f);
        conc[NH + tid] = fmaxf(pa, 0.f);
    }
    __syncthreads();
    if (tid < NAO) {
        float a = b_A[tid];
#pragma unroll
        for (int hh = 0; hh < 2 * NH; ++hh) a = fmaf(conc[hh], W_A[hh * NAO + tid], a);
        outA[(size_t)blockIdx.x * NAO + tid] = fmaxf(a, 0.f) * amask[blockIdx.x];
    }
}

extern "C" void kernel_launch(void* const* d_in, const int* in_sizes, int n_in,
                              void* d_out, int out_size, void* d_ws, size_t ws_size,
                              hipStream_t stream) {
    const float* atom  = (const float*)d_in[0];
    const float* pairf = (const float*)d_in[1];
    const float* amask = (const float*)d_in[2];
    const float* pmask = (const float*)d_in[3];
    const float* W_AA  = (const float*)d_in[4];
    const float* b_AA  = (const float*)d_in[5];
    const float* W_PA  = (const float*)d_in[6];
    const float* b_PA  = (const float*)d_in[7];
    const float* W_A   = (const float*)d_in[8];
    const float* b_A   = (const float*)d_in[9];
    const float* W_AP  = (const float*)d_in[10];
    const float* b_AP  = (const float*)d_in[11];
    const float* W_PP  = (const float*)d_in[12];
    const float* b_PP  = (const float*)d_in[13];
    const float* W_P   = (const float*)d_in[14];
    const float* b_P   = (const float*)d_in[15];

    unsigned short* t_ws  = (unsigned short*)d_ws;                    // 8192*72 bf16 = 1.18 MB
    unsigned short* wt_ws = (unsigned short*)((char*)d_ws + (size_t)NB * NM * 72 * 2); // 17.4 KB

    float* outA = (float*)d_out;
    float* outP = (float*)d_out + (size_t)NB * NM * NAO;

    k_t<<<(NB * NM * 72 + 255) / 256, 256, 0, stream>>>(atom, W_AP, t_ws);
    k_prep<<<(64 * 136 + 255) / 256, 256, 0, stream>>>(W_P, wt_ws);

    k_main<<<NB * NM, 256, 0, stream>>>(
        atom, pairf, amask, pmask,
        W_AA, b_AA, W_PA, b_PA, W_A, b_A, b_AP,
        W_PP, b_PP, b_P, t_ws, wt_ws, outA, outP);
}